// Round 11
// baseline (203.994 us; speedup 1.0000x reference)
//
#include <hip/hip_runtime.h>
#include <hip/hip_bf16.h>
#include <stdint.h>

#define BATCH 2
#define S_LEN 2048
#define EMB   1024
#define NHEAD 16
#define HDIM  64

typedef __attribute__((ext_vector_type(8)))  __bf16 bf16x8;
typedef __attribute__((ext_vector_type(4)))  __bf16 bf16x4;
typedef __attribute__((ext_vector_type(4)))  float  f32x4;
typedef __attribute__((ext_vector_type(16))) float  f32x16;

#define ZERO16 ((f32x16){0.f,0.f,0.f,0.f,0.f,0.f,0.f,0.f,0.f,0.f,0.f,0.f,0.f,0.f,0.f,0.f})
#define SM_SCALE_LOG2 0.18033688011112042f  /* 0.125 * log2(e) */

static __device__ __forceinline__ void gload_lds16(const void* g, void* l) {
    __builtin_amdgcn_global_load_lds(
        (__attribute__((address_space(1))) void*)g,
        (__attribute__((address_space(3))) void*)l,
        16, 0, 0);
}

// ---------------------------------------------------------------------------
// Fused fp32 -> bf16 conversion: x (1M float4) + 4 weights (256K float4 each)
// ---------------------------------------------------------------------------
__global__ void f2b_all(const float* __restrict__ x,
                        const float* __restrict__ Wq, const float* __restrict__ Wk,
                        const float* __restrict__ Wv, const float* __restrict__ Wo,
                        __bf16* __restrict__ xb,
                        __bf16* __restrict__ wqb, __bf16* __restrict__ wkb,
                        __bf16* __restrict__ wvb, __bf16* __restrict__ wob) {
    int i = blockIdx.x * blockDim.x + threadIdx.x;   // 0 .. 2097151
    const float* s;
    __bf16* d;
    int off;
    if (i < (1 << 20)) {
        s = x; d = xb; off = i;
    } else {
        int r   = i - (1 << 20);
        int seg = r >> 18;
        off = r & ((1 << 18) - 1);
        s = seg == 0 ? Wq : seg == 1 ? Wk : seg == 2 ? Wv : Wo;
        d = seg == 0 ? wqb : seg == 1 ? wkb : seg == 2 ? wvb : wob;
    }
    float4 v = reinterpret_cast<const float4*>(s)[off];
    bf16x4 o = { (__bf16)v.x, (__bf16)v.y, (__bf16)v.z, (__bf16)v.w };
    reinterpret_cast<bf16x4*>(d)[off] = o;
}

// ---------------------------------------------------------------------------
// 128x64-tile NT GEMM, fp32 out (final projection). Grid (N/64, M/128) = 512.
// Double-buffered LDS, 2-phase: stage(k+1) -> compute(k) -> barrier.
// ---------------------------------------------------------------------------
__global__ __launch_bounds__(256)
void gemm_o64(const __bf16* __restrict__ A, const __bf16* __restrict__ W,
              const float* __restrict__ bias, float* __restrict__ out,
              int M, int N, int K) {
    __shared__ __align__(16) __bf16 As[2][128 * 32];   // 16 KB
    __shared__ __align__(16) __bf16 Bs[2][64 * 32];    //  8 KB

    const int t    = threadIdx.x;
    const int w    = t >> 6;
    const int lane = t & 63;
    const int m0   = blockIdx.y * 128;
    const int n0   = blockIdx.x * 64;
    const int wr   = w * 32;
    const int fr   = lane & 15;
    const int kg   = (lane >> 4) * 8;

    f32x4 acc[2][4];
#pragma unroll
    for (int i = 0; i < 2; ++i)
#pragma unroll
        for (int n = 0; n < 4; ++n) acc[i][n] = (f32x4){0.f, 0.f, 0.f, 0.f};

    auto stage = [&](int kt, int buf) {
#pragma unroll
        for (int i = 0; i < 2; ++i) {
            int chunk = i * 256 + t;
            int row   = chunk >> 2;
            int col   = (chunk & 3) * 8;
            gload_lds16(A + (size_t)(m0 + row) * K + kt + col,
                        (char*)&As[buf][0] + i * 4096 + w * 1024);
        }
        {
            int row = t >> 2;
            int col = (t & 3) * 8;
            gload_lds16(W + (size_t)(n0 + row) * K + kt + col,
                        (char*)&Bs[buf][0] + w * 1024);
        }
    };

    stage(0, 0);
    __syncthreads();

    const int NK = K / 32;
    for (int k6 = 0; k6 < NK; ++k6) {
        const int cur = k6 & 1;
        if (k6 + 1 < NK) stage((k6 + 1) * 32, cur ^ 1);

        bf16x8 af[2], bfv[4];
#pragma unroll
        for (int m = 0; m < 2; ++m)
            af[m] = *(const bf16x8*)&As[cur][(wr + m * 16 + fr) * 32 + kg];
#pragma unroll
        for (int n = 0; n < 4; ++n)
            bfv[n] = *(const bf16x8*)&Bs[cur][(n * 16 + fr) * 32 + kg];
#pragma unroll
        for (int m = 0; m < 2; ++m)
#pragma unroll
            for (int n = 0; n < 4; ++n)
                acc[m][n] = __builtin_amdgcn_mfma_f32_16x16x32_bf16(
                    af[m], bfv[n], acc[m][n], 0, 0, 0);
        __syncthreads();
    }

    const int rbase = (lane >> 4) * 4;
#pragma unroll
    for (int m = 0; m < 2; ++m) {
#pragma unroll
        for (int n = 0; n < 4; ++n) {
            int col  = n0 + n * 16 + fr;
            float bv = bias[col];
#pragma unroll
            for (int jj = 0; jj < 4; ++jj) {
                int row = m0 + wr + m * 16 + rbase + jj;
                out[(size_t)row * N + col] = acc[m][n][jj] + bv;
            }
        }
    }
}

// ---------------------------------------------------------------------------
// Fused QKV projection, 128x128 tiles, double-buffered 2-phase K-loop.
// Grid x = 24 (which*8 + xx), y = 32.
// which 0/1 (Q,K): C = x . W^T  -> [B,H,S,HD].
// which 2   (V) : C = Wv . x^T -> V^T [B,H,HD,S]  (lane axis = s, coalesced).
// ---------------------------------------------------------------------------
__global__ __launch_bounds__(256)
void gemm_qkv(const __bf16* __restrict__ xb,
              const __bf16* __restrict__ Wqb, const __bf16* __restrict__ Wkb,
              const __bf16* __restrict__ Wvb,
              const float* __restrict__ bqp, const float* __restrict__ bkp,
              const float* __restrict__ bvp,
              __bf16* __restrict__ Qo, __bf16* __restrict__ Ko,
              __bf16* __restrict__ VTo, int K) {
    __shared__ __align__(16) __bf16 As[2][128 * 32];   // 16 KB
    __shared__ __align__(16) __bf16 Bs[2][128 * 32];   // 16 KB

    const int which = blockIdx.x >> 3;
    const int xx    = blockIdx.x & 7;

    const __bf16* Ap;
    const __bf16* Wp;
    int m0, n0;
    if (which == 2) {            // V^T: A = Wv (1024 rows), W = x (4096 rows)
        Ap = Wvb; Wp = xb;
        m0 = xx * 128;           // over (h,d)
        n0 = blockIdx.y * 128;   // over (b,s)
    } else {
        Ap = xb; Wp = (which == 0) ? Wqb : Wkb;
        m0 = blockIdx.y * 128;   // over (b,s)
        n0 = xx * 128;           // over (h,d)
    }
    const float* bias = which == 0 ? bqp : which == 1 ? bkp : bvp;

    const int t    = threadIdx.x;
    const int w    = t >> 6;
    const int lane = t & 63;
    const int wr   = (w >> 1) * 64;
    const int wc   = (w & 1) * 64;
    const int fr   = lane & 15;
    const int kg   = (lane >> 4) * 8;

    f32x4 acc[4][4];
#pragma unroll
    for (int i = 0; i < 4; ++i)
#pragma unroll
        for (int j = 0; j < 4; ++j) acc[i][j] = (f32x4){0.f, 0.f, 0.f, 0.f};

    auto stage = [&](int kt, int buf) {
#pragma unroll
        for (int i = 0; i < 2; ++i) {
            int chunk = i * 256 + t;
            int row   = chunk >> 2;
            int col   = (chunk & 3) * 8;
            gload_lds16(Ap + (size_t)(m0 + row) * K + kt + col,
                        (char*)&As[buf][0] + i * 4096 + w * 1024);
            gload_lds16(Wp + (size_t)(n0 + row) * K + kt + col,
                        (char*)&Bs[buf][0] + i * 4096 + w * 1024);
        }
    };

    stage(0, 0);
    __syncthreads();

    const int NK = K / 32;
    for (int k6 = 0; k6 < NK; ++k6) {
        const int cur = k6 & 1;
        if (k6 + 1 < NK) stage((k6 + 1) * 32, cur ^ 1);

        bf16x8 af[4], bfv[4];
#pragma unroll
        for (int m = 0; m < 4; ++m)
            af[m] = *(const bf16x8*)&As[cur][(wr + m * 16 + fr) * 32 + kg];
#pragma unroll
        for (int n = 0; n < 4; ++n)
            bfv[n] = *(const bf16x8*)&Bs[cur][(wc + n * 16 + fr) * 32 + kg];
#pragma unroll
        for (int m = 0; m < 4; ++m)
#pragma unroll
            for (int n = 0; n < 4; ++n)
                acc[m][n] = __builtin_amdgcn_mfma_f32_16x16x32_bf16(
                    af[m], bfv[n], acc[m][n], 0, 0, 0);
        __syncthreads();
    }

    const int rbase = (lane >> 4) * 4;
    if (which == 2) {
#pragma unroll
        for (int m = 0; m < 4; ++m) {
#pragma unroll
            for (int n = 0; n < 4; ++n) {
                int col = n0 + wc + n * 16 + fr;       // b*2048 + s
                int b   = col >> 11, s = col & (S_LEN - 1);
#pragma unroll
                for (int jj = 0; jj < 4; ++jj) {
                    int row = m0 + wr + m * 16 + rbase + jj;   // h*64 + d
                    int hh  = row >> 6, d = row & (HDIM - 1);
                    float v = acc[m][n][jj] + bias[row];
                    VTo[(((size_t)(b * NHEAD + hh)) * HDIM + d) * S_LEN + s] = (__bf16)v;
                }
            }
        }
    } else {
        __bf16* outp = (which == 0) ? Qo : Ko;
#pragma unroll
        for (int m = 0; m < 4; ++m) {
#pragma unroll
            for (int n = 0; n < 4; ++n) {
                int col  = n0 + wc + n * 16 + fr;
                float bv = bias[col];
#pragma unroll
                for (int jj = 0; jj < 4; ++jj) {
                    int row = m0 + wr + m * 16 + rbase + jj;
                    float v = acc[m][n][jj] + bv;
                    int b = row >> 11, s = row & (S_LEN - 1);
                    int hh = col >> 6, d = col & (HDIM - 1);
                    outp[(((size_t)(b * NHEAD + hh)) * S_LEN + s) * HDIM + d] = (__bf16)v;
                }
            }
        }
    }
}

// ---------------------------------------------------------------------------
// Block-causal flash attention, BARRIER-FREE main loop.
// Grid (x=bh 32, y=32), qt = 31-y (LPT). Block 512 thr = 8 waves:
// wave = (j in {0,1}) x (h4 in {0..3}); q-block qb = 2qt+j (32 rows); wave h4
// walks sub-blocks i = h4, h4+4, ... <= qb. K and V fragments are loaded
// DIRECTLY global->register (no LDS staging, no __syncthreads in the loop):
// per bh all blocks share one XCD's L2 (grid x=bh -> xcd=bh%8), K+V+Q=768KB
// L2-resident. K prefetched one sub-block ahead (ka/kn static rotation).
// LDS only: rescale broadcast (rare) + final 4-way merge.
// ---------------------------------------------------------------------------
__global__ __launch_bounds__(512, 4)
void attn8_kernel(const __bf16* __restrict__ Q, const __bf16* __restrict__ Kv,
                  const __bf16* __restrict__ VT, __bf16* __restrict__ out) {
    __shared__ __align__(16) char smem[51200];
    float* bc = (float*)(smem + 49152);          // aliases MLm (bc dead by merge)

    const int t    = threadIdx.x;
    const int w8   = t >> 6;
    const int lane = t & 63;
    const int h    = lane >> 5;
    const int q32  = lane & 31;
    const int j    = w8 & 1;
    const int h4   = w8 >> 1;
    const int bh   = blockIdx.x;               // 0..31
    const int qt   = 31 - blockIdx.y;          // heavy first (LPT)
    const int qb   = 2 * qt + j;               // this wave's q-block (32 rows)

    const __bf16* Qp  = Q  + (size_t)bh * S_LEN * HDIM;
    const __bf16* Kp  = Kv + (size_t)bh * S_LEN * HDIM;
    const __bf16* VTp = VT + (size_t)bh * HDIM * S_LEN;

    const int qrow = qb * 32 + q32;

    bf16x8 qreg[4];
#pragma unroll
    for (int ks = 0; ks < 4; ++ks)
        qreg[ks] = *(const bf16x8*)&Qp[(size_t)qrow * HDIM + 16 * ks + 8 * h];

    f32x16 oacc0 = ZERO16, oacc1 = ZERO16;
    float mrun = -1e30f, lrun = 0.f;

    // K fragment loader: sub-block i covers keys 32i..32i+31; lane reads
    // row (32i+q32), bytes [32ks+16h .. +16).
    auto loadK = [&](int i, bf16x8* dst) {
#pragma unroll
        for (int ks = 0; ks < 4; ++ks)
            dst[ks] = *(const bf16x8*)&Kp[(size_t)(i * 32 + q32) * 64 + 16 * ks + 8 * h];
    };

    auto step = [&](int i, const bf16x8* kf) {
        // S^T = K . Q^T
        f32x16 sac = ZERO16;
        __builtin_amdgcn_s_setprio(1);
#pragma unroll
        for (int ks = 0; ks < 4; ++ks)
            sac = __builtin_amdgcn_mfma_f32_32x32x16_bf16(kf[ks], qreg[ks], sac, 0, 0, 0);
        __builtin_amdgcn_s_setprio(0);

        // V fragments (consumed after softmax -> latency hides under it)
        bf16x8 vf0[2], vf1[2];
#pragma unroll
        for (int s2 = 0; s2 < 2; ++s2) {
            vf0[s2] = *(const bf16x8*)&VTp[(size_t)q32 * S_LEN + 32 * i + 16 * s2 + 8 * h];
            vf1[s2] = *(const bf16x8*)&VTp[(size_t)(32 + q32) * S_LEN + 32 * i + 16 * s2 + 8 * h];
        }

        float rmax = sac[0];
#pragma unroll
        for (int r = 1; r < 16; ++r) rmax = fmaxf(rmax, sac[r]);
        float pmax = rmax * SM_SCALE_LOG2;
        pmax = fmaxf(pmax, __shfl_xor(pmax, 32));

        if (__any(pmax > mrun + 8.f)) {
            float mnew = fmaxf(mrun, pmax);
            float fac  = exp2f(mrun - mnew);
            mrun = mnew;
            lrun *= fac;
            bc[w8 * 32 + q32] = fac;
            asm volatile("s_waitcnt lgkmcnt(0)" ::: "memory");
            __builtin_amdgcn_sched_barrier(0);
#pragma unroll
            for (int q2 = 0; q2 < 4; ++q2) {
                f32x4 fv = *(const f32x4*)&bc[w8 * 32 + 8 * q2 + 4 * h];
#pragma unroll
                for (int jj = 0; jj < 4; ++jj) {
                    oacc0[4 * q2 + jj] *= fv[jj];
                    oacc1[4 * q2 + jj] *= fv[jj];
                }
            }
        }

        float ps = 0.f;
#pragma unroll
        for (int r = 0; r < 16; ++r) {
            float pv = exp2f(__builtin_fmaf(sac[r], SM_SCALE_LOG2, -mrun));
            ps += pv;
            sac[r] = pv;
        }
        ps += __shfl_xor(ps, 32);
        lrun += ps;

        unsigned L[4], H[4];
#pragma unroll
        for (int g = 0; g < 4; ++g) {
            asm("v_cvt_pk_bf16_f32 %0, %1, %2"
                : "=v"(L[g]) : "v"(sac[4 * g]), "v"(sac[4 * g + 1]));
            asm("v_cvt_pk_bf16_f32 %0, %1, %2"
                : "=v"(H[g]) : "v"(sac[4 * g + 2]), "v"(sac[4 * g + 3]));
        }

        __builtin_amdgcn_s_setprio(1);
#pragma unroll
        for (int s2 = 0; s2 < 2; ++s2) {
            unsigned a0 = L[2 * s2], b0 = L[2 * s2 + 1];
            unsigned a1 = H[2 * s2], b1 = H[2 * s2 + 1];
            asm("v_permlane32_swap_b32 %0, %1" : "+v"(a0), "+v"(b0));
            asm("v_permlane32_swap_b32 %0, %1" : "+v"(a1), "+v"(b1));
            unsigned wvw[4] = { a0, a1, b0, b1 };
            bf16x8 pa = *(bf16x8*)wvw;
            oacc0 = __builtin_amdgcn_mfma_f32_32x32x16_bf16(pa, vf0[s2], oacc0, 0, 0, 0);
            oacc1 = __builtin_amdgcn_mfma_f32_32x32x16_bf16(pa, vf1[s2], oacc1, 0, 0, 0);
        }
        __builtin_amdgcn_s_setprio(0);
    };

    // main loop: stride-4 walk, K prefetched 1 sub-block ahead, 2x unrolled
    // so ka/kn rotate with static indexing (no scratch).
    {
        bf16x8 ka[4], kn[4];
        int i = h4;
        if (i <= qb) {
            loadK(i, ka);
            for (;;) {
                if (i + 4 <= qb) loadK(i + 4, kn);
                step(i, ka);
                i += 4;
                if (i > qb) break;
                if (i + 4 <= qb) loadK(i + 4, ka);
                step(i, kn);
                i += 4;
                if (i > qb) break;
            }
        }
    }

    // ---- 4-way merge: wave (j,0) <- waves (j,1..3) ----
    float* Oex = (float*)smem;                   // 6 slots x 8 KB = 48 KB
    float* MLm = (float*)(smem + 49152);         // [8][32]
    float* MLl = (float*)(smem + 50176);         // [8][32]

    __syncthreads();   // ensure all waves done with bc before ML overwrite
    if (h == 0) { MLm[w8 * 32 + q32] = mrun; MLl[w8 * 32 + q32] = lrun; }
    if (h4 != 0) {
        float* ob = Oex + (j * 3 + h4 - 1) * 2048;
#pragma unroll
        for (int q2 = 0; q2 < 4; ++q2)
#pragma unroll
            for (int jj = 0; jj < 4; ++jj) {
                int r  = 4 * q2 + jj;
                int rl = 8 * q2 + 4 * h + jj;
                ob[rl * 64 + q32]      = oacc0[r];
                ob[rl * 64 + 32 + q32] = oacc1[r];
            }
    }
    __syncthreads();

    if (h4 == 0) {
        const int b = bh >> 4, hh = bh & (NHEAD - 1);
        __bf16* op = out + (size_t)b * S_LEN * EMB + hh * HDIM;
        const float* ob1 = Oex + (j * 3 + 0) * 2048;
        const float* ob2 = Oex + (j * 3 + 1) * 2048;
        const float* ob3 = Oex + (j * 3 + 2) * 2048;
#pragma unroll
        for (int q2 = 0; q2 < 4; ++q2) {
            f32x4 mv[4], lv[4];
#pragma unroll
            for (int p = 0; p < 4; ++p) {
                int wp = (p << 1) | j;
                mv[p] = *(const f32x4*)&MLm[wp * 32 + 8 * q2 + 4 * h];
                lv[p] = *(const f32x4*)&MLl[wp * 32 + 8 * q2 + 4 * h];
            }
#pragma unroll
            for (int jj = 0; jj < 4; ++jj) {
                float mst = fmaxf(fmaxf(mv[0][jj], mv[1][jj]),
                                  fmaxf(mv[2][jj], mv[3][jj]));
                float s0 = exp2f(mv[0][jj] - mst);
                float s1 = exp2f(mv[1][jj] - mst);
                float s2 = exp2f(mv[2][jj] - mst);
                float s3 = exp2f(mv[3][jj] - mst);
                float inv = 1.f / (lv[0][jj] * s0 + lv[1][jj] * s1 +
                                   lv[2][jj] * s2 + lv[3][jj] * s3);
                int r  = 4 * q2 + jj;
                int rl = 8 * q2 + 4 * h + jj;
                int row = qb * 32 + rl;
                float v0 = (oacc0[r] * s0 + ob1[rl * 64 + q32] * s1 +
                            ob2[rl * 64 + q32] * s2 + ob3[rl * 64 + q32] * s3) * inv;
                float v1 = (oacc1[r] * s0 + ob1[rl * 64 + 32 + q32] * s1 +
                            ob2[rl * 64 + 32 + q32] * s2 + ob3[rl * 64 + 32 + q32] * s3) * inv;
                op[(size_t)row * EMB + q32]      = (__bf16)v0;
                op[(size_t)row * EMB + 32 + q32] = (__bf16)v1;
            }
        }
    }
}

// ---------------------------------------------------------------------------
extern "C" void kernel_launch(void* const* d_in, const int* in_sizes, int n_in,
                              void* d_out, int out_size, void* d_ws, size_t ws_size,
                              hipStream_t stream) {
    const float* x  = (const float*)d_in[0];
    const float* Wq = (const float*)d_in[1];
    const float* bq = (const float*)d_in[2];
    const float* Wk = (const float*)d_in[3];
    const float* bk = (const float*)d_in[4];
    const float* Wv = (const float*)d_in[5];
    const float* bv = (const float*)d_in[6];
    const float* Wo = (const float*)d_in[7];
    const float* bo = (const float*)d_in[8];
    float* out = (float*)d_out;

    char* ws = (char*)d_ws;
    __bf16* xb  = (__bf16*)(ws + 0);
    __bf16* wqb = (__bf16*)(ws + 8388608);
    __bf16* wkb = (__bf16*)(ws + 10485760);
    __bf16* wvb = (__bf16*)(ws + 12582912);
    __bf16* wob = (__bf16*)(ws + 14680064);
    __bf16* Qb  = (__bf16*)(ws + 16777216);
    __bf16* Kb  = (__bf16*)(ws + 25165824);
    __bf16* VTb = (__bf16*)(ws + 33554432);   // [B,H,HD,S] bf16
    __bf16* Ab  = (__bf16*)(ws + 41943040);

    const int M = BATCH * S_LEN;  // 4096
    const int N = EMB;            // 1024
    const int K = EMB;            // 1024

    f2b_all<<<8192, 256, 0, stream>>>(x, Wq, Wk, Wv, Wo, xb, wqb, wkb, wvb, wob);

    gemm_qkv<<<dim3(24, 32), 256, 0, stream>>>(
        xb, wqb, wkb, wvb, bq, bk, bv, Qb, Kb, VTb, K);

    attn8_kernel<<<dim3(BATCH * NHEAD, 32), 512, 0, stream>>>(Qb, Kb, VTb, Ab);

    gemm_o64<<<dim3(16, M / 128), 256, 0, stream>>>(Ab, wob, bo, out, M, N, K);
}

// Round 12
// 158.730 us; speedup vs baseline: 1.2852x; 1.2852x over previous
//
#include <hip/hip_runtime.h>
#include <hip/hip_bf16.h>
#include <stdint.h>

#define BATCH 2
#define S_LEN 2048
#define EMB   1024
#define NHEAD 16
#define HDIM  64

typedef __attribute__((ext_vector_type(8)))  __bf16 bf16x8;
typedef __attribute__((ext_vector_type(4)))  __bf16 bf16x4;
typedef __attribute__((ext_vector_type(4)))  float  f32x4;
typedef __attribute__((ext_vector_type(16))) float  f32x16;

#define ZERO16 ((f32x16){0.f,0.f,0.f,0.f,0.f,0.f,0.f,0.f,0.f,0.f,0.f,0.f,0.f,0.f,0.f,0.f})
#define SM_SCALE_LOG2 0.18033688011112042f  /* 0.125 * log2(e) */

static __device__ __forceinline__ void gload_lds16(const void* g, void* l) {
    __builtin_amdgcn_global_load_lds(
        (__attribute__((address_space(1))) void*)g,
        (__attribute__((address_space(3))) void*)l,
        16, 0, 0);
}

// ---------------------------------------------------------------------------
// Fused fp32 -> bf16 conversion: x (1M float4) + 4 weights (256K float4 each)
// ---------------------------------------------------------------------------
__global__ void f2b_all(const float* __restrict__ x,
                        const float* __restrict__ Wq, const float* __restrict__ Wk,
                        const float* __restrict__ Wv, const float* __restrict__ Wo,
                        __bf16* __restrict__ xb,
                        __bf16* __restrict__ wqb, __bf16* __restrict__ wkb,
                        __bf16* __restrict__ wvb, __bf16* __restrict__ wob) {
    int i = blockIdx.x * blockDim.x + threadIdx.x;   // 0 .. 2097151
    const float* s;
    __bf16* d;
    int off;
    if (i < (1 << 20)) {
        s = x; d = xb; off = i;
    } else {
        int r   = i - (1 << 20);
        int seg = r >> 18;
        off = r & ((1 << 18) - 1);
        s = seg == 0 ? Wq : seg == 1 ? Wk : seg == 2 ? Wv : Wo;
        d = seg == 0 ? wqb : seg == 1 ? wkb : seg == 2 ? wvb : wob;
    }
    float4 v = reinterpret_cast<const float4*>(s)[off];
    bf16x4 o = { (__bf16)v.x, (__bf16)v.y, (__bf16)v.z, (__bf16)v.w };
    reinterpret_cast<bf16x4*>(d)[off] = o;
}

// ---------------------------------------------------------------------------
// 128x64-tile NT GEMM, fp32 out (final projection). Grid (N/64, M/128) = 512.
// Double-buffered LDS, 2-phase: stage(k+1) -> compute(k) -> barrier.
// ---------------------------------------------------------------------------
__global__ __launch_bounds__(256)
void gemm_o64(const __bf16* __restrict__ A, const __bf16* __restrict__ W,
              const float* __restrict__ bias, float* __restrict__ out,
              int M, int N, int K) {
    __shared__ __align__(16) __bf16 As[2][128 * 32];   // 16 KB
    __shared__ __align__(16) __bf16 Bs[2][64 * 32];    //  8 KB

    const int t    = threadIdx.x;
    const int w    = t >> 6;
    const int lane = t & 63;
    const int m0   = blockIdx.y * 128;
    const int n0   = blockIdx.x * 64;
    const int wr   = w * 32;
    const int fr   = lane & 15;
    const int kg   = (lane >> 4) * 8;

    f32x4 acc[2][4];
#pragma unroll
    for (int i = 0; i < 2; ++i)
#pragma unroll
        for (int n = 0; n < 4; ++n) acc[i][n] = (f32x4){0.f, 0.f, 0.f, 0.f};

    auto stage = [&](int kt, int buf) {
#pragma unroll
        for (int i = 0; i < 2; ++i) {
            int chunk = i * 256 + t;
            int row   = chunk >> 2;
            int col   = (chunk & 3) * 8;
            gload_lds16(A + (size_t)(m0 + row) * K + kt + col,
                        (char*)&As[buf][0] + i * 4096 + w * 1024);
        }
        {
            int row = t >> 2;
            int col = (t & 3) * 8;
            gload_lds16(W + (size_t)(n0 + row) * K + kt + col,
                        (char*)&Bs[buf][0] + w * 1024);
        }
    };

    stage(0, 0);
    __syncthreads();

    const int NK = K / 32;
    for (int k6 = 0; k6 < NK; ++k6) {
        const int cur = k6 & 1;
        if (k6 + 1 < NK) stage((k6 + 1) * 32, cur ^ 1);

        bf16x8 af[2], bfv[4];
#pragma unroll
        for (int m = 0; m < 2; ++m)
            af[m] = *(const bf16x8*)&As[cur][(wr + m * 16 + fr) * 32 + kg];
#pragma unroll
        for (int n = 0; n < 4; ++n)
            bfv[n] = *(const bf16x8*)&Bs[cur][(n * 16 + fr) * 32 + kg];
#pragma unroll
        for (int m = 0; m < 2; ++m)
#pragma unroll
            for (int n = 0; n < 4; ++n)
                acc[m][n] = __builtin_amdgcn_mfma_f32_16x16x32_bf16(
                    af[m], bfv[n], acc[m][n], 0, 0, 0);
        __syncthreads();
    }

    const int rbase = (lane >> 4) * 4;
#pragma unroll
    for (int m = 0; m < 2; ++m) {
#pragma unroll
        for (int n = 0; n < 4; ++n) {
            int col  = n0 + n * 16 + fr;
            float bv = bias[col];
#pragma unroll
            for (int jj = 0; jj < 4; ++jj) {
                int row = m0 + wr + m * 16 + rbase + jj;
                out[(size_t)row * N + col] = acc[m][n][jj] + bv;
            }
        }
    }
}

// ---------------------------------------------------------------------------
// Fused QKV projection, 128x128 tiles, double-buffered 2-phase K-loop.
// Grid x = 24 (which*8 + xx), y = 32.
// which 0/1 (Q,K): C = x . W^T  -> [B,H,S,HD].
// which 2   (V) : C = Wv . x^T -> V^T [B,H,HD,S]  (lane axis = s, coalesced).
// ---------------------------------------------------------------------------
__global__ __launch_bounds__(256)
void gemm_qkv(const __bf16* __restrict__ xb,
              const __bf16* __restrict__ Wqb, const __bf16* __restrict__ Wkb,
              const __bf16* __restrict__ Wvb,
              const float* __restrict__ bqp, const float* __restrict__ bkp,
              const float* __restrict__ bvp,
              __bf16* __restrict__ Qo, __bf16* __restrict__ Ko,
              __bf16* __restrict__ VTo, int K) {
    __shared__ __align__(16) __bf16 As[2][128 * 32];   // 16 KB
    __shared__ __align__(16) __bf16 Bs[2][128 * 32];   // 16 KB

    const int which = blockIdx.x >> 3;
    const int xx    = blockIdx.x & 7;

    const __bf16* Ap;
    const __bf16* Wp;
    int m0, n0;
    if (which == 2) {            // V^T: A = Wv (1024 rows), W = x (4096 rows)
        Ap = Wvb; Wp = xb;
        m0 = xx * 128;           // over (h,d)
        n0 = blockIdx.y * 128;   // over (b,s)
    } else {
        Ap = xb; Wp = (which == 0) ? Wqb : Wkb;
        m0 = blockIdx.y * 128;   // over (b,s)
        n0 = xx * 128;           // over (h,d)
    }
    const float* bias = which == 0 ? bqp : which == 1 ? bkp : bvp;

    const int t    = threadIdx.x;
    const int w    = t >> 6;
    const int lane = t & 63;
    const int wr   = (w >> 1) * 64;
    const int wc   = (w & 1) * 64;
    const int fr   = lane & 15;
    const int kg   = (lane >> 4) * 8;

    f32x4 acc[4][4];
#pragma unroll
    for (int i = 0; i < 4; ++i)
#pragma unroll
        for (int j = 0; j < 4; ++j) acc[i][j] = (f32x4){0.f, 0.f, 0.f, 0.f};

    auto stage = [&](int kt, int buf) {
#pragma unroll
        for (int i = 0; i < 2; ++i) {
            int chunk = i * 256 + t;
            int row   = chunk >> 2;
            int col   = (chunk & 3) * 8;
            gload_lds16(Ap + (size_t)(m0 + row) * K + kt + col,
                        (char*)&As[buf][0] + i * 4096 + w * 1024);
            gload_lds16(Wp + (size_t)(n0 + row) * K + kt + col,
                        (char*)&Bs[buf][0] + i * 4096 + w * 1024);
        }
    };

    stage(0, 0);
    __syncthreads();

    const int NK = K / 32;
    for (int k6 = 0; k6 < NK; ++k6) {
        const int cur = k6 & 1;
        if (k6 + 1 < NK) stage((k6 + 1) * 32, cur ^ 1);

        bf16x8 af[4], bfv[4];
#pragma unroll
        for (int m = 0; m < 4; ++m)
            af[m] = *(const bf16x8*)&As[cur][(wr + m * 16 + fr) * 32 + kg];
#pragma unroll
        for (int n = 0; n < 4; ++n)
            bfv[n] = *(const bf16x8*)&Bs[cur][(wc + n * 16 + fr) * 32 + kg];
#pragma unroll
        for (int m = 0; m < 4; ++m)
#pragma unroll
            for (int n = 0; n < 4; ++n)
                acc[m][n] = __builtin_amdgcn_mfma_f32_16x16x32_bf16(
                    af[m], bfv[n], acc[m][n], 0, 0, 0);
        __syncthreads();
    }

    const int rbase = (lane >> 4) * 4;
    if (which == 2) {
#pragma unroll
        for (int m = 0; m < 4; ++m) {
#pragma unroll
            for (int n = 0; n < 4; ++n) {
                int col = n0 + wc + n * 16 + fr;       // b*2048 + s
                int b   = col >> 11, s = col & (S_LEN - 1);
#pragma unroll
                for (int jj = 0; jj < 4; ++jj) {
                    int row = m0 + wr + m * 16 + rbase + jj;   // h*64 + d
                    int hh  = row >> 6, d = row & (HDIM - 1);
                    float v = acc[m][n][jj] + bias[row];
                    VTo[(((size_t)(b * NHEAD + hh)) * HDIM + d) * S_LEN + s] = (__bf16)v;
                }
            }
        }
    } else {
        __bf16* outp = (which == 0) ? Qo : Ko;
#pragma unroll
        for (int m = 0; m < 4; ++m) {
#pragma unroll
            for (int n = 0; n < 4; ++n) {
                int col  = n0 + wc + n * 16 + fr;
                float bv = bias[col];
#pragma unroll
                for (int jj = 0; jj < 4; ++jj) {
                    int row = m0 + wr + m * 16 + rbase + jj;
                    float v = acc[m][n][jj] + bv;
                    int b = row >> 11, s = row & (S_LEN - 1);
                    int hh = col >> 6, d = col & (HDIM - 1);
                    outp[(((size_t)(b * NHEAD + hh)) * S_LEN + s) * HDIM + d] = (__bf16)v;
                }
            }
        }
    }
}

// ---------------------------------------------------------------------------
// Block-causal flash attention, BARRIER-FREE main loop, single-rotation
// K prefetch (register-budget fix of r11: one kf set, redefined after QK
// consumes it -> only one copy live; peak regs ~104 < 128 cap).
// Grid (x=bh 32, y=32), qt = 31-y (LPT). Block 512 thr = 8 waves:
// wave = (j in {0,1}) x (h4 in {0..3}); q-block qb = 2qt+j; wave h4 walks
// sub-blocks i = h4, h4+4, ... <= qb. K/V fragments loaded DIRECTLY
// global->register (per-bh K/V/Q = 768 KB, XCD-L2-resident via grid x=bh).
// LDS only: rescale broadcast (rare) + final 4-way merge.
// ---------------------------------------------------------------------------
__global__ __launch_bounds__(512, 4)
void attn9_kernel(const __bf16* __restrict__ Q, const __bf16* __restrict__ Kv,
                  const __bf16* __restrict__ VT, __bf16* __restrict__ out) {
    __shared__ __align__(16) char smem[51200];
    float* bc = (float*)(smem + 49152);          // aliases MLm (bc dead by merge)

    const int t    = threadIdx.x;
    const int w8   = t >> 6;
    const int lane = t & 63;
    const int h    = lane >> 5;
    const int q32  = lane & 31;
    const int j    = w8 & 1;
    const int h4   = w8 >> 1;
    const int bh   = blockIdx.x;               // 0..31
    const int qt   = 31 - blockIdx.y;          // heavy first (LPT)
    const int qb   = 2 * qt + j;               // this wave's q-block (32 rows)

    const __bf16* Qp  = Q  + (size_t)bh * S_LEN * HDIM;
    const __bf16* Kp  = Kv + (size_t)bh * S_LEN * HDIM;
    const __bf16* VTp = VT + (size_t)bh * HDIM * S_LEN;

    const int qrow = qb * 32 + q32;

    bf16x8 qreg[4];
#pragma unroll
    for (int ks = 0; ks < 4; ++ks)
        qreg[ks] = *(const bf16x8*)&Qp[(size_t)qrow * HDIM + 16 * ks + 8 * h];

    f32x16 oacc0 = ZERO16, oacc1 = ZERO16;
    float mrun = -1e30f, lrun = 0.f;

    if (h4 <= qb) {
        // initial K fragment (sub-block h4): lane reads row 32*h4+q32
        const __bf16* kp0 = &Kp[(size_t)(h4 * 32 + q32) * 64 + 8 * h];
        bf16x8 kf0 = *(const bf16x8*)(kp0);
        bf16x8 kf1 = *(const bf16x8*)(kp0 + 16);
        bf16x8 kf2 = *(const bf16x8*)(kp0 + 32);
        bf16x8 kf3 = *(const bf16x8*)(kp0 + 48);

        for (int i = h4; i <= qb; i += 4) {
            // ---- QK^T: S^T = K . Q^T (consumes kf*, then they are dead) ----
            f32x16 sac = ZERO16;
            __builtin_amdgcn_s_setprio(1);
            sac = __builtin_amdgcn_mfma_f32_32x32x16_bf16(kf0, qreg[0], sac, 0, 0, 0);
            sac = __builtin_amdgcn_mfma_f32_32x32x16_bf16(kf1, qreg[1], sac, 0, 0, 0);
            sac = __builtin_amdgcn_mfma_f32_32x32x16_bf16(kf2, qreg[2], sac, 0, 0, 0);
            sac = __builtin_amdgcn_mfma_f32_32x32x16_bf16(kf3, qreg[3], sac, 0, 0, 0);
            __builtin_amdgcn_s_setprio(0);

            // ---- rolling prefetch: redefine kf* with next sub-block's K ----
            if (i + 4 <= qb) {
                const __bf16* kp = &Kp[(size_t)((i + 4) * 32 + q32) * 64 + 8 * h];
                kf0 = *(const bf16x8*)(kp);
                kf1 = *(const bf16x8*)(kp + 16);
                kf2 = *(const bf16x8*)(kp + 32);
                kf3 = *(const bf16x8*)(kp + 48);
            }

            // ---- V fragments (latency hides under softmax) ----
            const __bf16* vp0 = &VTp[(size_t)q32 * S_LEN + 32 * i + 8 * h];
            const __bf16* vp1 = &VTp[(size_t)(32 + q32) * S_LEN + 32 * i + 8 * h];
            bf16x8 vf00 = *(const bf16x8*)(vp0);
            bf16x8 vf01 = *(const bf16x8*)(vp0 + 16);
            bf16x8 vf10 = *(const bf16x8*)(vp1);
            bf16x8 vf11 = *(const bf16x8*)(vp1 + 16);

            // ---- online softmax (log2 domain, scale folded into FMA) ----
            float rmax = sac[0];
#pragma unroll
            for (int r = 1; r < 16; ++r) rmax = fmaxf(rmax, sac[r]);
            float pmax = rmax * SM_SCALE_LOG2;
            pmax = fmaxf(pmax, __shfl_xor(pmax, 32));

            if (__any(pmax > mrun + 8.f)) {
                float mnew = fmaxf(mrun, pmax);
                float fac  = exp2f(mrun - mnew);
                mrun = mnew;
                lrun *= fac;
                bc[w8 * 32 + q32] = fac;
                asm volatile("s_waitcnt lgkmcnt(0)" ::: "memory");
                __builtin_amdgcn_sched_barrier(0);
#pragma unroll
                for (int q2 = 0; q2 < 4; ++q2) {
                    f32x4 fv = *(const f32x4*)&bc[w8 * 32 + 8 * q2 + 4 * h];
#pragma unroll
                    for (int jj = 0; jj < 4; ++jj) {
                        oacc0[4 * q2 + jj] *= fv[jj];
                        oacc1[4 * q2 + jj] *= fv[jj];
                    }
                }
            }

            float ps = 0.f;
#pragma unroll
            for (int r = 0; r < 16; ++r) {
                float pv = exp2f(__builtin_fmaf(sac[r], SM_SCALE_LOG2, -mrun));
                ps += pv;
                sac[r] = pv;
            }
            ps += __shfl_xor(ps, 32);
            lrun += ps;

            // ---- pack P to bf16 pairs ----
            unsigned L[4], H[4];
#pragma unroll
            for (int g = 0; g < 4; ++g) {
                asm("v_cvt_pk_bf16_f32 %0, %1, %2"
                    : "=v"(L[g]) : "v"(sac[4 * g]), "v"(sac[4 * g + 1]));
                asm("v_cvt_pk_bf16_f32 %0, %1, %2"
                    : "=v"(H[g]) : "v"(sac[4 * g + 2]), "v"(sac[4 * g + 3]));
            }

            // ---- PV ----
            __builtin_amdgcn_s_setprio(1);
            {
                unsigned a0 = L[0], b0 = L[1], a1 = H[0], b1 = H[1];
                asm("v_permlane32_swap_b32 %0, %1" : "+v"(a0), "+v"(b0));
                asm("v_permlane32_swap_b32 %0, %1" : "+v"(a1), "+v"(b1));
                unsigned wvw[4] = { a0, a1, b0, b1 };
                bf16x8 pa = *(bf16x8*)wvw;
                oacc0 = __builtin_amdgcn_mfma_f32_32x32x16_bf16(pa, vf00, oacc0, 0, 0, 0);
                oacc1 = __builtin_amdgcn_mfma_f32_32x32x16_bf16(pa, vf10, oacc1, 0, 0, 0);
            }
            {
                unsigned a0 = L[2], b0 = L[3], a1 = H[2], b1 = H[3];
                asm("v_permlane32_swap_b32 %0, %1" : "+v"(a0), "+v"(b0));
                asm("v_permlane32_swap_b32 %0, %1" : "+v"(a1), "+v"(b1));
                unsigned wvw[4] = { a0, a1, b0, b1 };
                bf16x8 pa = *(bf16x8*)wvw;
                oacc0 = __builtin_amdgcn_mfma_f32_32x32x16_bf16(pa, vf01, oacc0, 0, 0, 0);
                oacc1 = __builtin_amdgcn_mfma_f32_32x32x16_bf16(pa, vf11, oacc1, 0, 0, 0);
            }
            __builtin_amdgcn_s_setprio(0);
        }
    }

    // ---- 4-way merge: wave (j,0) <- waves (j,1..3) ----
    float* Oex = (float*)smem;                   // 6 slots x 8 KB = 48 KB
    float* MLm = (float*)(smem + 49152);         // [8][32]
    float* MLl = (float*)(smem + 50176);         // [8][32]

    __syncthreads();   // all waves done with bc before ML overwrite
    if (h == 0) { MLm[w8 * 32 + q32] = mrun; MLl[w8 * 32 + q32] = lrun; }
    if (h4 != 0) {
        float* ob = Oex + (j * 3 + h4 - 1) * 2048;
#pragma unroll
        for (int q2 = 0; q2 < 4; ++q2)
#pragma unroll
            for (int jj = 0; jj < 4; ++jj) {
                int r  = 4 * q2 + jj;
                int rl = 8 * q2 + 4 * h + jj;
                ob[rl * 64 + q32]      = oacc0[r];
                ob[rl * 64 + 32 + q32] = oacc1[r];
            }
    }
    __syncthreads();

    if (h4 == 0) {
        const int b = bh >> 4, hh = bh & (NHEAD - 1);
        __bf16* op = out + (size_t)b * S_LEN * EMB + hh * HDIM;
        const float* ob1 = Oex + (j * 3 + 0) * 2048;
        const float* ob2 = Oex + (j * 3 + 1) * 2048;
        const float* ob3 = Oex + (j * 3 + 2) * 2048;
#pragma unroll
        for (int q2 = 0; q2 < 4; ++q2) {
            f32x4 mv[4], lv[4];
#pragma unroll
            for (int p = 0; p < 4; ++p) {
                int wp = (p << 1) | j;
                mv[p] = *(const f32x4*)&MLm[wp * 32 + 8 * q2 + 4 * h];
                lv[p] = *(const f32x4*)&MLl[wp * 32 + 8 * q2 + 4 * h];
            }
#pragma unroll
            for (int jj = 0; jj < 4; ++jj) {
                float mst = fmaxf(fmaxf(mv[0][jj], mv[1][jj]),
                                  fmaxf(mv[2][jj], mv[3][jj]));
                float s0 = exp2f(mv[0][jj] - mst);
                float s1 = exp2f(mv[1][jj] - mst);
                float s2 = exp2f(mv[2][jj] - mst);
                float s3 = exp2f(mv[3][jj] - mst);
                float inv = 1.f / (lv[0][jj] * s0 + lv[1][jj] * s1 +
                                   lv[2][jj] * s2 + lv[3][jj] * s3);
                int r  = 4 * q2 + jj;
                int rl = 8 * q2 + 4 * h + jj;
                int row = qb * 32 + rl;
                float v0 = (oacc0[r] * s0 + ob1[rl * 64 + q32] * s1 +
                            ob2[rl * 64 + q32] * s2 + ob3[rl * 64 + q32] * s3) * inv;
                float v1 = (oacc1[r] * s0 + ob1[rl * 64 + 32 + q32] * s1 +
                            ob2[rl * 64 + 32 + q32] * s2 + ob3[rl * 64 + 32 + q32] * s3) * inv;
                op[(size_t)row * EMB + q32]      = (__bf16)v0;
                op[(size_t)row * EMB + 32 + q32] = (__bf16)v1;
            }
        }
    }
}

// ---------------------------------------------------------------------------
extern "C" void kernel_launch(void* const* d_in, const int* in_sizes, int n_in,
                              void* d_out, int out_size, void* d_ws, size_t ws_size,
                              hipStream_t stream) {
    const float* x  = (const float*)d_in[0];
    const float* Wq = (const float*)d_in[1];
    const float* bq = (const float*)d_in[2];
    const float* Wk = (const float*)d_in[3];
    const float* bk = (const float*)d_in[4];
    const float* Wv = (const float*)d_in[5];
    const float* bv = (const float*)d_in[6];
    const float* Wo = (const float*)d_in[7];
    const float* bo = (const float*)d_in[8];
    float* out = (float*)d_out;

    char* ws = (char*)d_ws;
    __bf16* xb  = (__bf16*)(ws + 0);
    __bf16* wqb = (__bf16*)(ws + 8388608);
    __bf16* wkb = (__bf16*)(ws + 10485760);
    __bf16* wvb = (__bf16*)(ws + 12582912);
    __bf16* wob = (__bf16*)(ws + 14680064);
    __bf16* Qb  = (__bf16*)(ws + 16777216);
    __bf16* Kb  = (__bf16*)(ws + 25165824);
    __bf16* VTb = (__bf16*)(ws + 33554432);   // [B,H,HD,S] bf16
    __bf16* Ab  = (__bf16*)(ws + 41943040);

    const int M = BATCH * S_LEN;  // 4096
    const int N = EMB;            // 1024
    const int K = EMB;            // 1024

    f2b_all<<<8192, 256, 0, stream>>>(x, Wq, Wk, Wv, Wo, xb, wqb, wkb, wvb, wob);

    gemm_qkv<<<dim3(24, 32), 256, 0, stream>>>(
        xb, wqb, wkb, wvb, bq, bk, bv, Qb, Kb, VTb, K);

    attn9_kernel<<<dim3(BATCH * NHEAD, 32), 512, 0, stream>>>(Qb, Kb, VTb, Ab);

    gemm_o64<<<dim3(16, M / 128), 256, 0, stream>>>(Ab, wob, bo, out, M, N, K);
}

// Round 13
// 119.993 us; speedup vs baseline: 1.7000x; 1.3228x over previous
//
#include <hip/hip_runtime.h>
#include <hip/hip_bf16.h>
#include <stdint.h>

#define BATCH 2
#define S_LEN 2048
#define EMB   1024
#define NHEAD 16
#define HDIM  64

typedef __attribute__((ext_vector_type(8)))  __bf16 bf16x8;
typedef __attribute__((ext_vector_type(4)))  __bf16 bf16x4;
typedef __attribute__((ext_vector_type(4)))  float  f32x4;
typedef __attribute__((ext_vector_type(16))) float  f32x16;

#define ZERO16 ((f32x16){0.f,0.f,0.f,0.f,0.f,0.f,0.f,0.f,0.f,0.f,0.f,0.f,0.f,0.f,0.f,0.f})
#define SM_SCALE_LOG2 0.18033688011112042f  /* 0.125 * log2(e) */

static __device__ __forceinline__ void gload_lds16(const void* g, void* l) {
    __builtin_amdgcn_global_load_lds(
        (__attribute__((address_space(1))) void*)g,
        (__attribute__((address_space(3))) void*)l,
        16, 0, 0);
}

// ---------------------------------------------------------------------------
// Fused fp32 -> bf16 conversion: x (1M float4) + 4 weights (256K float4 each)
// ---------------------------------------------------------------------------
__global__ void f2b_all(const float* __restrict__ x,
                        const float* __restrict__ Wq, const float* __restrict__ Wk,
                        const float* __restrict__ Wv, const float* __restrict__ Wo,
                        __bf16* __restrict__ xb,
                        __bf16* __restrict__ wqb, __bf16* __restrict__ wkb,
                        __bf16* __restrict__ wvb, __bf16* __restrict__ wob) {
    int i = blockIdx.x * blockDim.x + threadIdx.x;   // 0 .. 2097151
    const float* s;
    __bf16* d;
    int off;
    if (i < (1 << 20)) {
        s = x; d = xb; off = i;
    } else {
        int r   = i - (1 << 20);
        int seg = r >> 18;
        off = r & ((1 << 18) - 1);
        s = seg == 0 ? Wq : seg == 1 ? Wk : seg == 2 ? Wv : Wo;
        d = seg == 0 ? wqb : seg == 1 ? wkb : seg == 2 ? wvb : wob;
    }
    float4 v = reinterpret_cast<const float4*>(s)[off];
    bf16x4 o = { (__bf16)v.x, (__bf16)v.y, (__bf16)v.z, (__bf16)v.w };
    reinterpret_cast<bf16x4*>(d)[off] = o;
}

// ---------------------------------------------------------------------------
// 128x64-tile NT GEMM, fp32 out (final projection). Grid (N/64, M/128) = 512.
// Double-buffered LDS, 2-phase: stage(k+1) -> compute(k) -> barrier.
// ---------------------------------------------------------------------------
__global__ __launch_bounds__(256)
void gemm_o64(const __bf16* __restrict__ A, const __bf16* __restrict__ W,
              const float* __restrict__ bias, float* __restrict__ out,
              int M, int N, int K) {
    __shared__ __align__(16) __bf16 As[2][128 * 32];   // 16 KB
    __shared__ __align__(16) __bf16 Bs[2][64 * 32];    //  8 KB

    const int t    = threadIdx.x;
    const int w    = t >> 6;
    const int lane = t & 63;
    const int m0   = blockIdx.y * 128;
    const int n0   = blockIdx.x * 64;
    const int wr   = w * 32;
    const int fr   = lane & 15;
    const int kg   = (lane >> 4) * 8;

    f32x4 acc[2][4];
#pragma unroll
    for (int i = 0; i < 2; ++i)
#pragma unroll
        for (int n = 0; n < 4; ++n) acc[i][n] = (f32x4){0.f, 0.f, 0.f, 0.f};

    auto stage = [&](int kt, int buf) {
#pragma unroll
        for (int i = 0; i < 2; ++i) {
            int chunk = i * 256 + t;
            int row   = chunk >> 2;
            int col   = (chunk & 3) * 8;
            gload_lds16(A + (size_t)(m0 + row) * K + kt + col,
                        (char*)&As[buf][0] + i * 4096 + w * 1024);
        }
        {
            int row = t >> 2;
            int col = (t & 3) * 8;
            gload_lds16(W + (size_t)(n0 + row) * K + kt + col,
                        (char*)&Bs[buf][0] + w * 1024);
        }
    };

    stage(0, 0);
    __syncthreads();

    const int NK = K / 32;
    for (int k6 = 0; k6 < NK; ++k6) {
        const int cur = k6 & 1;
        if (k6 + 1 < NK) stage((k6 + 1) * 32, cur ^ 1);

        bf16x8 af[2], bfv[4];
#pragma unroll
        for (int m = 0; m < 2; ++m)
            af[m] = *(const bf16x8*)&As[cur][(wr + m * 16 + fr) * 32 + kg];
#pragma unroll
        for (int n = 0; n < 4; ++n)
            bfv[n] = *(const bf16x8*)&Bs[cur][(n * 16 + fr) * 32 + kg];
#pragma unroll
        for (int m = 0; m < 2; ++m)
#pragma unroll
            for (int n = 0; n < 4; ++n)
                acc[m][n] = __builtin_amdgcn_mfma_f32_16x16x32_bf16(
                    af[m], bfv[n], acc[m][n], 0, 0, 0);
        __syncthreads();
    }

    const int rbase = (lane >> 4) * 4;
#pragma unroll
    for (int m = 0; m < 2; ++m) {
#pragma unroll
        for (int n = 0; n < 4; ++n) {
            int col  = n0 + n * 16 + fr;
            float bv = bias[col];
#pragma unroll
            for (int jj = 0; jj < 4; ++jj) {
                int row = m0 + wr + m * 16 + rbase + jj;
                out[(size_t)row * N + col] = acc[m][n][jj] + bv;
            }
        }
    }
}

// ---------------------------------------------------------------------------
// Fused QKV projection, 128x128 tiles, double-buffered 2-phase K-loop.
// Grid x = 24 (which*8 + xx), y = 32.
// which 0/1 (Q,K): C = x . W^T  -> [B,H,S,HD].
// which 2   (V) : C = Wv . x^T -> V^T [B,H,HD,S]  (lane axis = s, coalesced).
// ---------------------------------------------------------------------------
__global__ __launch_bounds__(256)
void gemm_qkv(const __bf16* __restrict__ xb,
              const __bf16* __restrict__ Wqb, const __bf16* __restrict__ Wkb,
              const __bf16* __restrict__ Wvb,
              const float* __restrict__ bqp, const float* __restrict__ bkp,
              const float* __restrict__ bvp,
              __bf16* __restrict__ Qo, __bf16* __restrict__ Ko,
              __bf16* __restrict__ VTo, int K) {
    __shared__ __align__(16) __bf16 As[2][128 * 32];   // 16 KB
    __shared__ __align__(16) __bf16 Bs[2][128 * 32];   // 16 KB

    const int which = blockIdx.x >> 3;
    const int xx    = blockIdx.x & 7;

    const __bf16* Ap;
    const __bf16* Wp;
    int m0, n0;
    if (which == 2) {            // V^T: A = Wv (1024 rows), W = x (4096 rows)
        Ap = Wvb; Wp = xb;
        m0 = xx * 128;           // over (h,d)
        n0 = blockIdx.y * 128;   // over (b,s)
    } else {
        Ap = xb; Wp = (which == 0) ? Wqb : Wkb;
        m0 = blockIdx.y * 128;   // over (b,s)
        n0 = xx * 128;           // over (h,d)
    }
    const float* bias = which == 0 ? bqp : which == 1 ? bkp : bvp;

    const int t    = threadIdx.x;
    const int w    = t >> 6;
    const int lane = t & 63;
    const int wr   = (w >> 1) * 64;
    const int wc   = (w & 1) * 64;
    const int fr   = lane & 15;
    const int kg   = (lane >> 4) * 8;

    f32x4 acc[4][4];
#pragma unroll
    for (int i = 0; i < 4; ++i)
#pragma unroll
        for (int j = 0; j < 4; ++j) acc[i][j] = (f32x4){0.f, 0.f, 0.f, 0.f};

    auto stage = [&](int kt, int buf) {
#pragma unroll
        for (int i = 0; i < 2; ++i) {
            int chunk = i * 256 + t;
            int row   = chunk >> 2;
            int col   = (chunk & 3) * 8;
            gload_lds16(Ap + (size_t)(m0 + row) * K + kt + col,
                        (char*)&As[buf][0] + i * 4096 + w * 1024);
            gload_lds16(Wp + (size_t)(n0 + row) * K + kt + col,
                        (char*)&Bs[buf][0] + i * 4096 + w * 1024);
        }
    };

    stage(0, 0);
    __syncthreads();

    const int NK = K / 32;
    for (int k6 = 0; k6 < NK; ++k6) {
        const int cur = k6 & 1;
        if (k6 + 1 < NK) stage((k6 + 1) * 32, cur ^ 1);

        bf16x8 af[4], bfv[4];
#pragma unroll
        for (int m = 0; m < 4; ++m)
            af[m] = *(const bf16x8*)&As[cur][(wr + m * 16 + fr) * 32 + kg];
#pragma unroll
        for (int n = 0; n < 4; ++n)
            bfv[n] = *(const bf16x8*)&Bs[cur][(wc + n * 16 + fr) * 32 + kg];
#pragma unroll
        for (int m = 0; m < 4; ++m)
#pragma unroll
            for (int n = 0; n < 4; ++n)
                acc[m][n] = __builtin_amdgcn_mfma_f32_16x16x32_bf16(
                    af[m], bfv[n], acc[m][n], 0, 0, 0);
        __syncthreads();
    }

    const int rbase = (lane >> 4) * 4;
    if (which == 2) {
#pragma unroll
        for (int m = 0; m < 4; ++m) {
#pragma unroll
            for (int n = 0; n < 4; ++n) {
                int col = n0 + wc + n * 16 + fr;       // b*2048 + s
                int b   = col >> 11, s = col & (S_LEN - 1);
#pragma unroll
                for (int jj = 0; jj < 4; ++jj) {
                    int row = m0 + wr + m * 16 + rbase + jj;   // h*64 + d
                    int hh  = row >> 6, d = row & (HDIM - 1);
                    float v = acc[m][n][jj] + bias[row];
                    VTo[(((size_t)(b * NHEAD + hh)) * HDIM + d) * S_LEN + s] = (__bf16)v;
                }
            }
        }
    } else {
        __bf16* outp = (which == 0) ? Qo : Ko;
#pragma unroll
        for (int m = 0; m < 4; ++m) {
#pragma unroll
            for (int n = 0; n < 4; ++n) {
                int col  = n0 + wc + n * 16 + fr;
                float bv = bias[col];
#pragma unroll
                for (int jj = 0; jj < 4; ++jj) {
                    int row = m0 + wr + m * 16 + rbase + jj;
                    float v = acc[m][n][jj] + bv;
                    int b = row >> 11, s = row & (S_LEN - 1);
                    int hh = col >> 6, d = col & (HDIM - 1);
                    outp[(((size_t)(b * NHEAD + hh)) * S_LEN + s) * HDIM + d] = (__bf16)v;
                }
            }
        }
    }
}

// ---------------------------------------------------------------------------
// Block-causal flash attention: q-tile 128 (4 q-blocks), 8 waves =
// (j in {0..3}) x (kv-half h2 in {0,1}). Grid (x=bh 32, y=16); qt remap
// (y<8)?15-y:y-8 so each CU's 2 co-resident blocks sum to constant 17 chunks
// (all 512 blocks co-resident at 2/CU). Per 128-key chunk (C = qt+1 chunks):
//   issue V_c -> Vt (single buffer), issue K_{c+1} -> Kt[cur^1]
//   u=0: QK+softmax (Kt[cur]) -> barrier (V ready) -> u=0 PV
//   u=1: QK+softmax+PV -> barrier (Vt reads done)
// Wave (j,h2) handles global sub-blocks g = 4c+2h2+u, active iff g <= qb.
// 2-way LDS merge (h2 pairs) at the end. Same live-register set as attn7.
// ---------------------------------------------------------------------------
__global__ __launch_bounds__(512, 4)
void attn10_kernel(const __bf16* __restrict__ Q, const __bf16* __restrict__ Kv,
                   const __bf16* __restrict__ VT, __bf16* __restrict__ out) {
    __shared__ __align__(16) char smem[51200];
    __bf16* Kt0 = (__bf16*)smem;                 // Kt[2][128*64] = 32 KB
    __bf16* Vt  = (__bf16*)(smem + 32768);       // Vt[64*128]    = 16 KB
    float*  bc  = (float*)(smem + 49152);        // [8][32] (aliases MLm)

    const int t    = threadIdx.x;
    const int w8   = t >> 6;
    const int lane = t & 63;
    const int h    = lane >> 5;
    const int q32  = lane & 31;
    const int j    = w8 & 3;
    const int h2   = w8 >> 2;
    const int bh   = blockIdx.x;               // 0..31
    const int yy   = blockIdx.y;               // 0..15
    const int qt   = (yy < 8) ? (15 - yy) : (yy - 8);  // CU pair sums const
    const int qb   = 4 * qt + j;               // this wave's q-block (32 rows)
    const int C    = qt + 1;                   // 128-key chunks

    const __bf16* Qp  = Q  + (size_t)bh * S_LEN * HDIM;
    const __bf16* Kp  = Kv + (size_t)bh * S_LEN * HDIM;
    const __bf16* VTp = VT + (size_t)bh * HDIM * S_LEN;

    const int qrow = qb * 32 + q32;

    bf16x8 qreg[4];
#pragma unroll
    for (int ks = 0; ks < 4; ++ks)
        qreg[ks] = *(const bf16x8*)&Qp[(size_t)qrow * HDIM + 16 * ks + 8 * h];

    f32x16 oacc0 = ZERO16, oacc1 = ZERO16;
    float mrun = -1e30f, lrun = 0.f;

    // prologue: K chunk 0 -> buffer 0
    {
#pragma unroll
        for (int i = 0; i < 2; ++i) {
            int c16 = i * 512 + t;
            int key = c16 >> 3;
            int d0  = ((c16 & 7) ^ (key & 7)) * 8;
            gload_lds16(Kp + (size_t)key * HDIM + d0, (char*)Kt0 + c16 * 16);
        }
        __syncthreads();
    }

    for (int c = 0; c < C; ++c) {
        const int cur = c & 1;
        // issue V_c (single buffer; free since last chunk's 2nd barrier)
        {
            const int kb = c * 128;
#pragma unroll
            for (int i = 0; i < 2; ++i) {
                int c16 = i * 512 + t;
                int d   = c16 >> 4;
                int o   = c16 & 15;
                gload_lds16(VTp + (size_t)d * S_LEN + kb + ((o ^ (d & 7)) * 8),
                            (char*)Vt + c16 * 16);
            }
        }
        // issue K_{c+1}
        if (c + 1 < C) {
            const int kb = (c + 1) * 128;
#pragma unroll
            for (int i = 0; i < 2; ++i) {
                int c16 = i * 512 + t;
                int key = c16 >> 3;
                int d0  = ((c16 & 7) ^ (key & 7)) * 8;
                gload_lds16(Kp + (size_t)(kb + key) * HDIM + d0,
                            (char*)Kt0 + (cur ^ 1) * 16384 + c16 * 16);
            }
        }

        const int  g0 = 4 * c + 2 * h2;       // global sub-block of u=0
        const bool w0 = (g0 <= qb);
        const bool w1 = (g0 + 1 <= qb);
        const int  kl0 = 64 * h2;             // local key base, u=0
        const __bf16* Ktc = Kt0 + cur * 8192;

        unsigned L[4], H[4];                  // u=0 P, carried across barrier
        if (w0) {
            // ---- u=0: S^T = K . Q^T ----
            f32x16 sac = ZERO16;
            __builtin_amdgcn_s_setprio(1);
#pragma unroll
            for (int ks = 0; ks < 4; ++ks) {
                bf16x8 kf = *(const bf16x8*)&Ktc[(kl0 + q32) * 64 +
                                ((16 * ks + 8 * h) ^ ((q32 & 7) << 3))];
                sac = __builtin_amdgcn_mfma_f32_32x32x16_bf16(kf, qreg[ks], sac, 0, 0, 0);
            }
            __builtin_amdgcn_s_setprio(0);

            float rmax = sac[0];
#pragma unroll
            for (int r = 1; r < 16; ++r) rmax = fmaxf(rmax, sac[r]);
            float pmax = rmax * SM_SCALE_LOG2;
            pmax = fmaxf(pmax, __shfl_xor(pmax, 32));

            if (__any(pmax > mrun + 8.f)) {
                float mnew = fmaxf(mrun, pmax);
                float fac  = exp2f(mrun - mnew);
                mrun = mnew;
                lrun *= fac;
                bc[w8 * 32 + q32] = fac;
                asm volatile("s_waitcnt lgkmcnt(0)" ::: "memory");
                __builtin_amdgcn_sched_barrier(0);
#pragma unroll
                for (int q2 = 0; q2 < 4; ++q2) {
                    f32x4 fv = *(const f32x4*)&bc[w8 * 32 + 8 * q2 + 4 * h];
#pragma unroll
                    for (int jj = 0; jj < 4; ++jj) {
                        oacc0[4 * q2 + jj] *= fv[jj];
                        oacc1[4 * q2 + jj] *= fv[jj];
                    }
                }
            }

            float ps = 0.f;
#pragma unroll
            for (int r = 0; r < 16; ++r) {
                float pv = exp2f(__builtin_fmaf(sac[r], SM_SCALE_LOG2, -mrun));
                ps += pv;
                sac[r] = pv;
            }
            ps += __shfl_xor(ps, 32);
            lrun += ps;

#pragma unroll
            for (int g = 0; g < 4; ++g) {
                asm("v_cvt_pk_bf16_f32 %0, %1, %2"
                    : "=v"(L[g]) : "v"(sac[4 * g]), "v"(sac[4 * g + 1]));
                asm("v_cvt_pk_bf16_f32 %0, %1, %2"
                    : "=v"(H[g]) : "v"(sac[4 * g + 2]), "v"(sac[4 * g + 3]));
            }
        }

        __syncthreads();   // V_c staged & visible (drains vmcnt)

        if (w0) {
            // ---- u=0 PV ----
            __builtin_amdgcn_s_setprio(1);
#pragma unroll
            for (int s2 = 0; s2 < 2; ++s2) {
                unsigned a0 = L[2 * s2], b0 = L[2 * s2 + 1];
                unsigned a1 = H[2 * s2], b1 = H[2 * s2 + 1];
                asm("v_permlane32_swap_b32 %0, %1" : "+v"(a0), "+v"(b0));
                asm("v_permlane32_swap_b32 %0, %1" : "+v"(a1), "+v"(b1));
                unsigned wvw[4] = { a0, a1, b0, b1 };
                bf16x8 pa = *(bf16x8*)wvw;

                const int klb = kl0 + 16 * s2 + 8 * h;
#pragma unroll
                for (int n = 0; n < 2; ++n) {
                    int d = 32 * n + q32;
                    bf16x8 vf = *(const bf16x8*)&Vt[d * 128 +
                                    (klb ^ ((d & 7) << 3))];
                    if (n == 0)
                        oacc0 = __builtin_amdgcn_mfma_f32_32x32x16_bf16(pa, vf, oacc0, 0, 0, 0);
                    else
                        oacc1 = __builtin_amdgcn_mfma_f32_32x32x16_bf16(pa, vf, oacc1, 0, 0, 0);
                }
            }
            __builtin_amdgcn_s_setprio(0);
        }

        if (w1) {
            // ---- u=1: QK + softmax + PV (V already available) ----
            const int kl1 = kl0 + 32;
            f32x16 sac = ZERO16;
            __builtin_amdgcn_s_setprio(1);
#pragma unroll
            for (int ks = 0; ks < 4; ++ks) {
                bf16x8 kf = *(const bf16x8*)&Ktc[(kl1 + q32) * 64 +
                                ((16 * ks + 8 * h) ^ ((q32 & 7) << 3))];
                sac = __builtin_amdgcn_mfma_f32_32x32x16_bf16(kf, qreg[ks], sac, 0, 0, 0);
            }
            __builtin_amdgcn_s_setprio(0);

            float rmax = sac[0];
#pragma unroll
            for (int r = 1; r < 16; ++r) rmax = fmaxf(rmax, sac[r]);
            float pmax = rmax * SM_SCALE_LOG2;
            pmax = fmaxf(pmax, __shfl_xor(pmax, 32));

            if (__any(pmax > mrun + 8.f)) {
                float mnew = fmaxf(mrun, pmax);
                float fac  = exp2f(mrun - mnew);
                mrun = mnew;
                lrun *= fac;
                bc[w8 * 32 + q32] = fac;
                asm volatile("s_waitcnt lgkmcnt(0)" ::: "memory");
                __builtin_amdgcn_sched_barrier(0);
#pragma unroll
                for (int q2 = 0; q2 < 4; ++q2) {
                    f32x4 fv = *(const f32x4*)&bc[w8 * 32 + 8 * q2 + 4 * h];
#pragma unroll
                    for (int jj = 0; jj < 4; ++jj) {
                        oacc0[4 * q2 + jj] *= fv[jj];
                        oacc1[4 * q2 + jj] *= fv[jj];
                    }
                }
            }

            float ps = 0.f;
#pragma unroll
            for (int r = 0; r < 16; ++r) {
                float pv = exp2f(__builtin_fmaf(sac[r], SM_SCALE_LOG2, -mrun));
                ps += pv;
                sac[r] = pv;
            }
            ps += __shfl_xor(ps, 32);
            lrun += ps;

            unsigned L1[4], H1[4];
#pragma unroll
            for (int g = 0; g < 4; ++g) {
                asm("v_cvt_pk_bf16_f32 %0, %1, %2"
                    : "=v"(L1[g]) : "v"(sac[4 * g]), "v"(sac[4 * g + 1]));
                asm("v_cvt_pk_bf16_f32 %0, %1, %2"
                    : "=v"(H1[g]) : "v"(sac[4 * g + 2]), "v"(sac[4 * g + 3]));
            }

            __builtin_amdgcn_s_setprio(1);
#pragma unroll
            for (int s2 = 0; s2 < 2; ++s2) {
                unsigned a0 = L1[2 * s2], b0 = L1[2 * s2 + 1];
                unsigned a1 = H1[2 * s2], b1 = H1[2 * s2 + 1];
                asm("v_permlane32_swap_b32 %0, %1" : "+v"(a0), "+v"(b0));
                asm("v_permlane32_swap_b32 %0, %1" : "+v"(a1), "+v"(b1));
                unsigned wvw[4] = { a0, a1, b0, b1 };
                bf16x8 pa = *(bf16x8*)wvw;

                const int klb = kl1 + 16 * s2 + 8 * h;
#pragma unroll
                for (int n = 0; n < 2; ++n) {
                    int d = 32 * n + q32;
                    bf16x8 vf = *(const bf16x8*)&Vt[d * 128 +
                                    (klb ^ ((d & 7) << 3))];
                    if (n == 0)
                        oacc0 = __builtin_amdgcn_mfma_f32_32x32x16_bf16(pa, vf, oacc0, 0, 0, 0);
                    else
                        oacc1 = __builtin_amdgcn_mfma_f32_32x32x16_bf16(pa, vf, oacc1, 0, 0, 0);
                }
            }
            __builtin_amdgcn_s_setprio(0);
        }

        __syncthreads();   // all Vt/Kt[cur] reads done; next buffers ready
    }

    // ---- 2-way merge: wave (j, h2=0) <- wave (j, h2=1) ----
    float* Oex = (float*)smem;                   // 4 slots x 8 KB = 32 KB
    float* MLm = (float*)(smem + 49152);         // [8][32]
    float* MLl = (float*)(smem + 50176);         // [8][32]

    if (h == 0) { MLm[w8 * 32 + q32] = mrun; MLl[w8 * 32 + q32] = lrun; }
    if (h2 == 1) {
        float* ob = Oex + j * 2048;
#pragma unroll
        for (int q2 = 0; q2 < 4; ++q2)
#pragma unroll
            for (int jj = 0; jj < 4; ++jj) {
                int r  = 4 * q2 + jj;
                int rl = 8 * q2 + 4 * h + jj;
                ob[rl * 64 + q32]      = oacc0[r];
                ob[rl * 64 + 32 + q32] = oacc1[r];
            }
    }
    __syncthreads();

    if (h2 == 0) {
        const int b = bh >> 4, hh = bh & (NHEAD - 1);
        __bf16* op = out + (size_t)b * S_LEN * EMB + hh * HDIM;
        const float* ob = Oex + j * 2048;
#pragma unroll
        for (int q2 = 0; q2 < 4; ++q2) {
            f32x4 ma4 = *(const f32x4*)&MLm[j * 32 + 8 * q2 + 4 * h];
            f32x4 mb4 = *(const f32x4*)&MLm[(j + 4) * 32 + 8 * q2 + 4 * h];
            f32x4 la4 = *(const f32x4*)&MLl[j * 32 + 8 * q2 + 4 * h];
            f32x4 lb4 = *(const f32x4*)&MLl[(j + 4) * 32 + 8 * q2 + 4 * h];
#pragma unroll
            for (int jj = 0; jj < 4; ++jj) {
                float ma = ma4[jj], mb = mb4[jj];
                float mst = fmaxf(ma, mb);
                float sa  = exp2f(ma - mst), sb = exp2f(mb - mst);
                float inv = 1.f / (la4[jj] * sa + lb4[jj] * sb);
                int r  = 4 * q2 + jj;
                int rl = 8 * q2 + 4 * h + jj;
                int row = qb * 32 + rl;
                float v0 = (oacc0[r] * sa + ob[rl * 64 + q32] * sb) * inv;
                float v1 = (oacc1[r] * sa + ob[rl * 64 + 32 + q32] * sb) * inv;
                op[(size_t)row * EMB + q32]      = (__bf16)v0;
                op[(size_t)row * EMB + 32 + q32] = (__bf16)v1;
            }
        }
    }
}

// ---------------------------------------------------------------------------
extern "C" void kernel_launch(void* const* d_in, const int* in_sizes, int n_in,
                              void* d_out, int out_size, void* d_ws, size_t ws_size,
                              hipStream_t stream) {
    const float* x  = (const float*)d_in[0];
    const float* Wq = (const float*)d_in[1];
    const float* bq = (const float*)d_in[2];
    const float* Wk = (const float*)d_in[3];
    const float* bk = (const float*)d_in[4];
    const float* Wv = (const float*)d_in[5];
    const float* bv = (const float*)d_in[6];
    const float* Wo = (const float*)d_in[7];
    const float* bo = (const float*)d_in[8];
    float* out = (float*)d_out;

    char* ws = (char*)d_ws;
    __bf16* xb  = (__bf16*)(ws + 0);
    __bf16* wqb = (__bf16*)(ws + 8388608);
    __bf16* wkb = (__bf16*)(ws + 10485760);
    __bf16* wvb = (__bf16*)(ws + 12582912);
    __bf16* wob = (__bf16*)(ws + 14680064);
    __bf16* Qb  = (__bf16*)(ws + 16777216);
    __bf16* Kb  = (__bf16*)(ws + 25165824);
    __bf16* VTb = (__bf16*)(ws + 33554432);   // [B,H,HD,S] bf16
    __bf16* Ab  = (__bf16*)(ws + 41943040);

    const int M = BATCH * S_LEN;  // 4096
    const int N = EMB;            // 1024
    const int K = EMB;            // 1024

    f2b_all<<<8192, 256, 0, stream>>>(x, Wq, Wk, Wv, Wo, xb, wqb, wkb, wvb, wob);

    gemm_qkv<<<dim3(24, 32), 256, 0, stream>>>(
        xb, wqb, wkb, wvb, bq, bk, bv, Qb, Kb, VTb, K);

    attn10_kernel<<<dim3(BATCH * NHEAD, 16), 512, 0, stream>>>(Qb, Kb, VTb, Ab);

    gemm_o64<<<dim3(16, M / 128), 256, 0, stream>>>(Ab, wob, bo, out, M, N, K);
}